// Round 13
// baseline (1007.896 us; speedup 1.0000x reference)
//
#include <hip/hip_runtime.h>
#include <hip/hip_bf16.h>
#include <math.h>

#define N_NODES 100000
#define N_EDGES 3200000
#define F_IN 128
#define HID 256
#define KCL 30
#define NCOPY 8

typedef unsigned int uint;
typedef unsigned short ushort;
typedef unsigned char uchar;
typedef __attribute__((ext_vector_type(8))) short bf16x8;
typedef __attribute__((ext_vector_type(4))) float f32x4;
typedef __attribute__((ext_vector_type(2))) float f32x2;

static __device__ __forceinline__ float bf2f(ushort u) {
  return __uint_as_float(((uint)u) << 16);
}
static __device__ __forceinline__ ushort f2bf(float f) {
  uint u = __float_as_uint(f);
  uint r = (u + 0x7FFF + ((u >> 16) & 1)) >> 16;   // round-to-nearest-even
  return (ushort)r;
}

// ---- fp8 e4m3 (OCP) encode/decode: HW cvt if available, software fallback ----
static __device__ __forceinline__ uchar f2fp8(float f) {
#if __has_builtin(__builtin_amdgcn_cvt_pk_fp8_f32)
  return (uchar)(__builtin_amdgcn_cvt_pk_fp8_f32(f, f, 0, false) & 0xFF);
#else
  uint u = __float_as_uint(f);
  uint s = (u >> 24) & 0x80u;
  float a = fabsf(f);
  if (a >= 448.f) return (uchar)(s | 0x7E);
  if (a < 0.015625f) {
    int q = (int)rintf(a * 512.f);
    return (uchar)(s | (q > 8 ? 8 : q));
  }
  int e = ((int)((u >> 23) & 0xFF)) - 127;
  float step = __uint_as_float((uint)(127 + e - 3) << 23);
  int q = (int)rintf(a / step);
  if (q == 16) { e += 1; q = 8; }
  return (uchar)(s | ((e + 7) << 3) | (q - 8));
#endif
}
static __device__ __forceinline__ float fp82f_sw(uchar b) {
  uint s = ((uint)(b & 0x80u)) << 24;
  uint em = b & 0x7Fu;
  float mag;
  if ((em >> 3) == 0) mag = (float)em * 0.001953125f;
  else mag = __uint_as_float((((em >> 3) + 120) << 23) | ((em & 7u) << 20));
  return __uint_as_float(s | __float_as_uint(mag));
}
static __device__ __forceinline__ void fp8x4_dec(uint u, float* o) {
#if __has_builtin(__builtin_amdgcn_cvt_pk_f32_fp8)
  f32x2 lo = __builtin_amdgcn_cvt_pk_f32_fp8((int)u, false);
  f32x2 hi = __builtin_amdgcn_cvt_pk_f32_fp8((int)u, true);
  o[0] = lo.x; o[1] = lo.y; o[2] = hi.x; o[3] = hi.y;
#else
  o[0] = fp82f_sw(u & 0xFF); o[1] = fp82f_sw((u >> 8) & 0xFF);
  o[2] = fp82f_sw((u >> 16) & 0xFF); o[3] = fp82f_sw((u >> 24) & 0xFF);
#endif
}
static __device__ __forceinline__ float fp81_dec(uchar b) {
#if __has_builtin(__builtin_amdgcn_cvt_pk_f32_fp8)
  f32x2 lo = __builtin_amdgcn_cvt_pk_f32_fp8((int)(uint)b, false);
  return lo.x;
#else
  return fp82f_sw(b);
#endif
}
static __device__ __forceinline__ void dec29(uint4 lo, uint4 hi, float* f) {
  fp8x4_dec(lo.x, f + 0);  fp8x4_dec(lo.y, f + 4);
  fp8x4_dec(lo.z, f + 8);  fp8x4_dec(lo.w, f + 12);
  fp8x4_dec(hi.x, f + 16); fp8x4_dec(hi.y, f + 20);
  fp8x4_dec(hi.z, f + 24);
  f[28] = fp81_dec((uchar)(hi.w & 0xFF));
}

// scal layout: [0]=m, [1]=connectivity, [2..31]=colsum(30), [32..60]=svec(29)
// cd8 layout: int2 {cnt, deg_w(float bits)} per (copy g, node n), interleaved.

// ---------- cnt8: XCD-privatized {edge-count, weighted-degree} histogram + m, 4 edges/thread ----------
__global__ __launch_bounds__(256) void k_cnt8(const int* __restrict__ ei,
                                              const float* __restrict__ w,
                                              int* __restrict__ cd8,
                                              float* __restrict__ m_out) {
  int e0 = (blockIdx.x * 256 + threadIdx.x) * 4;
  int g = blockIdx.x & (NCOPY - 1);
  int4 cc = *(const int4*)(ei + N_EDGES + e0);
  float4 ww = *(const float4*)(w + e0);
  int* tab = cd8 + (size_t)g * N_NODES * 2;
  atomicAdd(tab + (size_t)cc.x * 2, 1);
  atomicAdd((float*)(tab + (size_t)cc.x * 2 + 1), ww.x);
  atomicAdd(tab + (size_t)cc.y * 2, 1);
  atomicAdd((float*)(tab + (size_t)cc.y * 2 + 1), ww.y);
  atomicAdd(tab + (size_t)cc.z * 2, 1);
  atomicAdd((float*)(tab + (size_t)cc.z * 2 + 1), ww.z);
  atomicAdd(tab + (size_t)cc.w * 2, 1);
  atomicAdd((float*)(tab + (size_t)cc.w * 2 + 1), ww.w);
  float s = ww.x + ww.y + ww.z + ww.w;
  #pragma unroll
  for (int o = 32; o > 0; o >>= 1) s += __shfl_down(s, o);
  __shared__ float ls[4];
  int lane = threadIdx.x & 63, wid = threadIdx.x >> 6;
  if (lane == 0) ls[wid] = s;
  __syncthreads();
  if (threadIdx.x == 0) atomicAdd(m_out, ls[0] + ls[1] + ls[2] + ls[3]);
}

// ---------- dis: reduce 8 deg copies -> dis = rsqrt(deg + 1) ----------
__global__ __launch_bounds__(256) void k_dis(const int* __restrict__ cd8,
                                             float* __restrict__ dis) {
  int n = blockIdx.x * 256 + threadIdx.x;
  if (n >= N_NODES) return;
  float s = 0.f;
  #pragma unroll
  for (int g = 0; g < NCOPY; ++g)
    s += __int_as_float(cd8[((size_t)g * N_NODES + n) * 2 + 1]);
  dis[n] = rsqrtf(s + 1.f);
}

// ---------- scanA ----------
__global__ __launch_bounds__(1024) void k_scanA(const int* __restrict__ cd8,
                                                int* __restrict__ off8,
                                                int* __restrict__ blocktot) {
  __shared__ int wsum[16];
  const int t = threadIdx.x;
  const int lane = t & 63, wid = t >> 6;
  int node = blockIdx.x * 1024 + t;
  int v[NCOPY];
  int tot = 0;
  if (node < N_NODES) {
    #pragma unroll
    for (int g = 0; g < NCOPY; ++g) {
      int x = cd8[((size_t)g * N_NODES + node) * 2];
      v[g] = tot;
      tot += x;
    }
  } else {
    #pragma unroll
    for (int g = 0; g < NCOPY; ++g) v[g] = 0;
  }
  int x = tot;
  #pragma unroll
  for (int o = 1; o < 64; o <<= 1) {
    int y = __shfl_up(x, o);
    if (lane >= o) x += y;
  }
  if (lane == 63) wsum[wid] = x;
  __syncthreads();
  if (t < 16) {
    int s = wsum[t];
    #pragma unroll
    for (int o = 1; o < 16; o <<= 1) {
      int y = __shfl_up(s, o);
      if (t >= o) s += y;
    }
    wsum[t] = s;
  }
  __syncthreads();
  int excl = (wid ? wsum[wid - 1] : 0) + x - tot;
  if (node < N_NODES) {
    #pragma unroll
    for (int g = 0; g < NCOPY; ++g) off8[(size_t)node * NCOPY + g] = excl + v[g];
  }
  if (t == 0) blocktot[blockIdx.x] = wsum[15];
}

// ---------- scanB ----------
__global__ void k_scanB(const int* __restrict__ blocktot, int* __restrict__ blockoff) {
  if (threadIdx.x == 0 && blockIdx.x == 0) {
    int acc = 0;
    for (int b = 0; b < 98; ++b) { blockoff[b] = acc; acc += blocktot[b]; }
  }
}

// ---------- scanC ----------
__global__ __launch_bounds__(256) void k_scanC(int* __restrict__ off8,
                                               const int* __restrict__ blockoff) {
  int idx = blockIdx.x * 256 + threadIdx.x;
  if (idx > N_NODES * NCOPY) return;
  if (idx == N_NODES * NCOPY) { off8[idx] = N_EDGES; return; }
  off8[idx] += blockoff[idx >> 13];
}

// ---------- csrfill8: 4 edges/thread; store (src, pn = w*dis[src]) directly ----------
__global__ __launch_bounds__(256) void k_csrfill8(const int* __restrict__ ei,
                                                  const float* __restrict__ w,
                                                  const float* __restrict__ dis,
                                                  int* __restrict__ cd8,
                                                  const int* __restrict__ off8,
                                                  int2* __restrict__ csr) {
  int e0 = (blockIdx.x * 256 + threadIdx.x) * 4;
  int g = blockIdx.x & (NCOPY - 1);
  int4 rr = *(const int4*)(ei + e0);
  int4 cc = *(const int4*)(ei + N_EDGES + e0);
  float4 ww = *(const float4*)(w + e0);
  int* tab = cd8 + (size_t)g * N_NODES * 2;
  const int rA[4] = {rr.x, rr.y, rr.z, rr.w};
  const int cA[4] = {cc.x, cc.y, cc.z, cc.w};
  const float wA[4] = {ww.x, ww.y, ww.z, ww.w};
  float pn[4];
  #pragma unroll
  for (int q = 0; q < 4; ++q) pn[q] = wA[q] * dis[rA[q]];   // dis: 400KB, L2-resident
  int idx[4];
  #pragma unroll
  for (int q = 0; q < 4; ++q) idx[q] = atomicSub(tab + (size_t)cA[q] * 2, 1) - 1;
  int pos[4];
  #pragma unroll
  for (int q = 0; q < 4; ++q) pos[q] = off8[(size_t)cA[q] * NCOPY + g] + idx[q];
  #pragma unroll
  for (int q = 0; q < 4; ++q) csr[pos[q]] = make_int2(rA[q], __float_as_int(pn[q]));
}

// ---------- wprep ----------
__global__ __launch_bounds__(256) void k_wprep(const float* __restrict__ Wc,
                                               const float* __restrict__ Wl,
                                               ushort* __restrict__ WT1) {
  int idx = blockIdx.x * 256 + threadIdx.x;
  int vc = idx >> 5;
  int kq = (idx & 31) * 4;
  const float* W = (vc < HID) ? Wc : Wl;
  int c = vc & (HID - 1);
  ushort4 u;
  u.x = f2bf(W[(size_t)(kq + 0) * HID + c]);
  u.y = f2bf(W[(size_t)(kq + 1) * HID + c]);
  u.z = f2bf(W[(size_t)(kq + 2) * HID + c]);
  u.w = f2bf(W[(size_t)(kq + 3) * HID + c]);
  *(ushort4*)(WT1 + (size_t)vc * F_IN + kq) = u;
}

// ---------- wprep2 ----------
__global__ __launch_bounds__(256) void k_wprep2(const float* __restrict__ Wc,
                                                const float* __restrict__ Wl,
                                                ushort* __restrict__ WT2) {
  int idx = blockIdx.x * 256 + threadIdx.x;
  int vc = idx >> 6;
  int kq = (idx & 63) * 4;
  const float* W = (vc < 32) ? Wc : Wl;
  int c = vc & 31;
  ushort4 u = make_ushort4(0, 0, 0, 0);
  if (c < KCL) {
    u.x = f2bf(W[(size_t)(kq + 0) * KCL + c]);
    u.y = f2bf(W[(size_t)(kq + 1) * KCL + c]);
    u.z = f2bf(W[(size_t)(kq + 2) * KCL + c]);
    u.w = f2bf(W[(size_t)(kq + 3) * KCL + c]);
  }
  *(ushort4*)(WT2 + (size_t)vc * HID + kq) = u;
}

// ---------- layer-1 dual GEMM via MFMA bf16; hconv out fp8 (LDS repack), base1 out bf16 ----------
__global__ __launch_bounds__(256) void k_gemm1m(const float* __restrict__ x,
                                                const ushort* __restrict__ WT1,
                                                const float* __restrict__ bc,
                                                const float* __restrict__ bl,
                                                const float* __restrict__ dis,
                                                uchar* __restrict__ hconv_f8,
                                                ushort* __restrict__ base1b) {
  __shared__ ushort xs[32 * F_IN];   // 8 KB: bf16 x-tile, then reused as fp8 [32][256] tile
  uchar* xs8 = (uchar*)xs;
  const int t = threadIdx.x;
  const int lane = t & 63, wid = t >> 6;
  const int m0 = blockIdx.x * 32;
  {
    int row = t >> 3, k0 = (t & 7) * 16;
    const float4* xp = (const float4*)(x + (size_t)(m0 + row) * F_IN + k0);
    #pragma unroll
    for (int q = 0; q < 4; ++q) {
      float4 v = xp[q];
      ushort4 u = make_ushort4(f2bf(v.x), f2bf(v.y), f2bf(v.z), f2bf(v.w));
      int k = k0 + q * 4;
      *(ushort4*)&xs[row * F_IN + (k ^ ((row & 7) << 3))] = u;
    }
  }
  __syncthreads();
  const int r0 = lane & 15, r1 = 16 + (lane & 15);
  const int kb = (lane >> 4) * 8;
  bf16x8 A0[4], A1[4];
  #pragma unroll
  for (int ks = 0; ks < 4; ++ks) {
    int k = ks * 32 + kb;
    A0[ks] = *(const bf16x8*)&xs[r0 * F_IN + (k ^ ((r0 & 7) << 3))];
    A1[ks] = *(const bf16x8*)&xs[r1 * F_IN + (k ^ ((r1 & 7) << 3))];
  }
  __syncthreads();   // all waves done reading xs; safe to overwrite with fp8 bytes
  const int rb = (lane >> 4) * 4;
  #pragma unroll
  for (int cb = 0; cb < 2; ++cb) {
    bf16x8 B[4][4];   // f = cs*2+cf: {C0,C1,L0,L1}
    const int vbase = cb * 128 + wid * 32 + (lane & 15);
    #pragma unroll
    for (int cs = 0; cs < 2; ++cs)
      #pragma unroll
      for (int cf = 0; cf < 2; ++cf)
        #pragma unroll
        for (int ks = 0; ks < 4; ++ks) {
          int vc = cs * HID + vbase + cf * 16;
          B[cs * 2 + cf][ks] = *(const bf16x8*)(WT1 + (size_t)vc * F_IN + ks * 32 + kb);
        }
    f32x4 acc[2][4];
    #pragma unroll
    for (int fm = 0; fm < 2; ++fm)
      #pragma unroll
      for (int f = 0; f < 4; ++f) acc[fm][f] = (f32x4){0.f, 0.f, 0.f, 0.f};
    #pragma unroll
    for (int ks = 0; ks < 4; ++ks) {
      #pragma unroll
      for (int f = 0; f < 4; ++f) {
        acc[0][f] = __builtin_amdgcn_mfma_f32_16x16x32_bf16(A0[ks], B[f][ks], acc[0][f], 0, 0, 0);
        acc[1][f] = __builtin_amdgcn_mfma_f32_16x16x32_bf16(A1[ks], B[f][ks], acc[1][f], 0, 0, 0);
      }
    }
    #pragma unroll
    for (int cf = 0; cf < 2; ++cf) {
      int c = cb * 128 + wid * 32 + cf * 16 + (lane & 15);
      float bcv = bc[c], blv = bl[c];
      #pragma unroll
      for (int fm = 0; fm < 2; ++fm) {
        #pragma unroll
        for (int r = 0; r < 4; ++r) {
          int lrow = fm * 16 + rb + r;
          int row = m0 + lrow;
          float hc = acc[fm][cf][r];
          float hl = acc[fm][2 + cf][r];
          float d = dis[row];
          xs8[lrow * 256 + c] = f2fp8(hc);
          base1b[(size_t)row * HID + c] = f2bf(hl + blv + bcv + d * d * hc);
        }
      }
    }
  }
  __syncthreads();
  {
    int row = t >> 3, c0 = (t & 7) * 32;
    uint4 a = *(const uint4*)&xs8[row * 256 + c0];
    uint4 b = *(const uint4*)&xs8[row * 256 + c0 + 16];
    uchar* dst = hconv_f8 + (size_t)(m0 + row) * 256 + c0;
    *(uint4*)dst = a;
    *(uint4*)(dst + 16) = b;
  }
}

// ---------- layer-1 aggregation over fp8 hconv (4-deep gather pipeline) ----------
__global__ __launch_bounds__(256) void k_agg1(const int* __restrict__ off8,
                                              const int2* __restrict__ csr,
                                              const uint* __restrict__ hconv_u32,
                                              const ushort* __restrict__ base1b,
                                              const float* __restrict__ dis,
                                              ushort* __restrict__ h1b) {
  const int n = blockIdx.x;
  const int t = threadIdx.x;
  const int lane = t & 63, wid = t >> 6;
  const int e0 = off8[(size_t)n * NCOPY];
  const int e1 = off8[(size_t)(n + 1) * NCOPY];
  __shared__ int2 s_e[256];
  __shared__ float red[4][256];
  float acc0 = 0.f, acc1 = 0.f, acc2 = 0.f, acc3 = 0.f;
  for (int jb = e0; jb < e1; jb += 256) {
    int cn = min(256, e1 - jb);
    __syncthreads();
    if (t < cn) s_e[t] = csr[jb + t];
    __syncthreads();
    int j = wid;
    for (; j + 12 < cn; j += 16) {
      int2 eA = s_e[j];
      int2 eB = s_e[j + 4];
      int2 eC = s_e[j + 8];
      int2 eD = s_e[j + 12];
      uint uA = hconv_u32[(size_t)eA.x * 64 + lane];
      uint uB = hconv_u32[(size_t)eB.x * 64 + lane];
      uint uC = hconv_u32[(size_t)eC.x * 64 + lane];
      uint uD = hconv_u32[(size_t)eD.x * 64 + lane];
      float nA = __int_as_float(eA.y);
      float nB = __int_as_float(eB.y);
      float nC = __int_as_float(eC.y);
      float nD = __int_as_float(eD.y);
      float vA[4], vB[4], vC[4], vD[4];
      fp8x4_dec(uA, vA);
      fp8x4_dec(uB, vB);
      fp8x4_dec(uC, vC);
      fp8x4_dec(uD, vD);
      acc0 = fmaf(nA, vA[0], acc0); acc1 = fmaf(nA, vA[1], acc1);
      acc2 = fmaf(nA, vA[2], acc2); acc3 = fmaf(nA, vA[3], acc3);
      acc0 = fmaf(nB, vB[0], acc0); acc1 = fmaf(nB, vB[1], acc1);
      acc2 = fmaf(nB, vB[2], acc2); acc3 = fmaf(nB, vB[3], acc3);
      acc0 = fmaf(nC, vC[0], acc0); acc1 = fmaf(nC, vC[1], acc1);
      acc2 = fmaf(nC, vC[2], acc2); acc3 = fmaf(nC, vC[3], acc3);
      acc0 = fmaf(nD, vD[0], acc0); acc1 = fmaf(nD, vD[1], acc1);
      acc2 = fmaf(nD, vD[2], acc2); acc3 = fmaf(nD, vD[3], acc3);
    }
    for (; j + 4 < cn; j += 8) {
      int2 eA = s_e[j];
      int2 eB = s_e[j + 4];
      float nA = __int_as_float(eA.y);
      float nB = __int_as_float(eB.y);
      uint uA = hconv_u32[(size_t)eA.x * 64 + lane];
      uint uB = hconv_u32[(size_t)eB.x * 64 + lane];
      float vA[4], vB[4];
      fp8x4_dec(uA, vA);
      fp8x4_dec(uB, vB);
      acc0 = fmaf(nA, vA[0], acc0); acc1 = fmaf(nA, vA[1], acc1);
      acc2 = fmaf(nA, vA[2], acc2); acc3 = fmaf(nA, vA[3], acc3);
      acc0 = fmaf(nB, vB[0], acc0); acc1 = fmaf(nB, vB[1], acc1);
      acc2 = fmaf(nB, vB[2], acc2); acc3 = fmaf(nB, vB[3], acc3);
    }
    if (j < cn) {
      int2 eA = s_e[j];
      float nA = __int_as_float(eA.y);
      uint uA = hconv_u32[(size_t)eA.x * 64 + lane];
      float vA[4];
      fp8x4_dec(uA, vA);
      acc0 = fmaf(nA, vA[0], acc0); acc1 = fmaf(nA, vA[1], acc1);
      acc2 = fmaf(nA, vA[2], acc2); acc3 = fmaf(nA, vA[3], acc3);
    }
  }
  __syncthreads();
  ((float4*)red[wid])[lane] = make_float4(acc0, acc1, acc2, acc3);
  __syncthreads();
  float dn = dis[n];
  float v = dn * (red[0][t] + red[1][t] + red[2][t] + red[3][t]) + bf2f(base1b[(size_t)n * HID + t]);
  h1b[(size_t)n * HID + t] = f2bf(fmaxf(v, 0.f));
}

// ---------- layer-2 dual GEMM via MFMA bf16; hconv2 out fp8 (stride 32 B) ----------
__global__ __launch_bounds__(256) void k_gemm2m(const ushort* __restrict__ h1b,
                                                const ushort* __restrict__ WT2,
                                                const float* __restrict__ bc,
                                                const float* __restrict__ bl,
                                                const float* __restrict__ dis,
                                                uchar* __restrict__ hconv2f8,
                                                float* __restrict__ base2p) {
  __shared__ ushort hs[64 * HID];    // 32 KB, XOR-swizzled bf16
  const int t = threadIdx.x;
  const int lane = t & 63, wid = t >> 6;
  const int n0 = blockIdx.x * 64;
  {
    int row = t >> 2, kq = (t & 3) * 64;
    int gn = n0 + row;
    #pragma unroll
    for (int q = 0; q < 8; ++q) {
      int k = kq + q * 8;
      uint4 u = make_uint4(0, 0, 0, 0);
      if (gn < N_NODES) u = *(const uint4*)(h1b + (size_t)gn * HID + k);
      *(uint4*)&hs[row * HID + (k ^ ((row & 7) << 3))] = u;
    }
  }
  __syncthreads();
  const int lr = wid * 16 + (lane & 15);
  const int kb = (lane >> 4) * 8;
  f32x4 acc[4];
  #pragma unroll
  for (int f = 0; f < 4; ++f) acc[f] = (f32x4){0.f, 0.f, 0.f, 0.f};
  #pragma unroll
  for (int ks = 0; ks < 8; ++ks) {
    int k = ks * 32 + kb;
    bf16x8 A = *(const bf16x8*)&hs[lr * HID + (k ^ ((lr & 7) << 3))];
    #pragma unroll
    for (int f = 0; f < 4; ++f) {
      int vc = f * 16 + (lane & 15);
      bf16x8 B = *(const bf16x8*)(WT2 + (size_t)vc * HID + k);
      acc[f] = __builtin_amdgcn_mfma_f32_16x16x32_bf16(A, B, acc[f], 0, 0, 0);
    }
  }
  const int rb = (lane >> 4) * 4;
  #pragma unroll
  for (int cf = 0; cf < 2; ++cf) {
    int c = cf * 16 + (lane & 15);
    if (c < KCL) {
      float bcv = bc[c], blv = bl[c];
      #pragma unroll
      for (int r = 0; r < 4; ++r) {
        int row = n0 + wid * 16 + rb + r;
        if (row < N_NODES) {
          float hc = acc[cf][r];
          float hl = acc[2 + cf][r];
          float d = dis[row];
          hconv2f8[(size_t)row * 32 + c] = f2fp8(hc);
          base2p[(size_t)row * 32 + c] = hl + blv + bcv + d * d * hc;
        }
      }
    }
  }
}

// ---------- layer-2 aggregation + softmax + FX(fp32) + FXb8(fp8, stride 32B) + colsum ----------
__global__ __launch_bounds__(256) void k_agg2(const int* __restrict__ off8,
                                              const int2* __restrict__ csr,
                                              const float* __restrict__ dis,
                                              const uchar* __restrict__ hconv2f8,
                                              const float* __restrict__ base2p,
                                              float* __restrict__ FX,
                                              uchar* __restrict__ FXb8,
                                              float* __restrict__ scal) {
  const int t = threadIdx.x;
  const int lane = t & 63, wid = t >> 6;
  const int half = lane >> 5, c = lane & 31;
  const int nwaves = gridDim.x * 4;
  const int gw = blockIdx.x * 4 + wid;
  float cs_acc = 0.f;
  for (int n = gw; n < N_NODES; n += nwaves) {
    int e0 = off8[(size_t)n * NCOPY];
    int e1 = off8[(size_t)(n + 1) * NCOPY];
    float accA = 0.f, accB = 0.f;
    int j = e0 + half;
    for (; j + 2 < e1; j += 4) {
      int2 eA = csr[j];
      int2 eB = csr[j + 2];
      float p0 = __int_as_float(eA.y);
      float p1 = __int_as_float(eB.y);
      uchar b0 = hconv2f8[(size_t)eA.x * 32 + c];
      uchar b1 = hconv2f8[(size_t)eB.x * 32 + c];
      float v0 = (c < KCL) ? fp81_dec(b0) : 0.f;
      float v1 = (c < KCL) ? fp81_dec(b1) : 0.f;
      accA = fmaf(p0, v0, accA);
      accB = fmaf(p1, v1, accB);
    }
    if (j < e1) {
      int2 eA = csr[j];
      float p0 = __int_as_float(eA.y);
      uchar b0 = hconv2f8[(size_t)eA.x * 32 + c];
      float v0 = (c < KCL) ? fp81_dec(b0) : 0.f;
      accA = fmaf(p0, v0, accA);
    }
    float acc = accA + accB;
    acc += __shfl(acc, lane ^ 32);
    float out = (c < KCL) ? acc * dis[n] + base2p[(size_t)n * 32 + c] : -1e30f;
    float mx = out;
    #pragma unroll
    for (int o = 16; o > 0; o >>= 1) mx = fmaxf(mx, __shfl_xor(mx, o));
    float p = (c < KCL) ? __expf(out - mx) : 0.f;
    float sum = p;
    #pragma unroll
    for (int o = 16; o > 0; o >>= 1) sum += __shfl_xor(sum, o);
    float fx = p / sum;
    fx = fminf(fmaxf(fx, 1e-9f), 1.f - 1e-9f);
    if (half == 0 && c < KCL) {
      FX[(size_t)n * KCL + c] = fx;
      FXb8[(size_t)n * 32 + c] = f2fp8(fx);
    }
    cs_acc += (c < KCL) ? fx : 0.f;
  }
  __shared__ float red_cs[4][32];
  if (half == 0) red_cs[wid][c] = cs_acc;
  __syncthreads();
  if (t < KCL) {
    float a = red_cs[0][t] + red_cs[1][t] + red_cs[2][t] + red_cs[3][t];
    atomicAdd(&scal[2 + t], a);
  }
}

// ---------- connectivity + svec, edge-parallel over fp8 FX shadow (32 B rows, L2-resident) ----------
__global__ __launch_bounds__(256) void k_conn(const int* __restrict__ ei,
                                              const float* __restrict__ w,
                                              const uchar* __restrict__ FXb8,
                                              float* __restrict__ scal) {
  const int t = threadIdx.x;
  const int lane = t & 63, wid = t >> 6;
  const size_t e0 = ((size_t)blockIdx.x * 256 + t) * 4;
  float sv[29];
  #pragma unroll
  for (int k = 0; k < 29; ++k) sv[k] = 0.f;
  float conn = 0.f;
  int4 rr = *(const int4*)(ei + e0);
  int4 cc = *(const int4*)(ei + N_EDGES + e0);
  float4 ww = *(const float4*)(w + e0);
  const int rA[4] = {rr.x, rr.y, rr.z, rr.w};
  const int cA[4] = {cc.x, cc.y, cc.z, cc.w};
  const float wA[4] = {ww.x, ww.y, ww.z, ww.w};
  #pragma unroll
  for (int q = 0; q < 4; ++q) {
    int r = rA[q], cN = cA[q];
    float wv = wA[q];
    uint4 alo = *(const uint4*)(FXb8 + (size_t)r * 32);
    uint4 ahi = *(const uint4*)(FXb8 + (size_t)r * 32 + 16);
    uint4 blo = *(const uint4*)(FXb8 + (size_t)cN * 32);
    uint4 bhi = *(const uint4*)(FXb8 + (size_t)cN * 32 + 16);
    float fa[29], fb[29];
    dec29(alo, ahi, fa);
    dec29(blo, bhi, fb);
    float dot = 0.f;
    #pragma unroll
    for (int k = 0; k < 29; ++k) {
      dot += fa[k] * fb[k];
      sv[k] = fmaf(wv, fa[k], sv[k]);
    }
    conn = fmaf(wv, dot, conn);
  }
  __shared__ float red[4][30];
  #pragma unroll
  for (int i = 0; i < 30; ++i) {
    float v = (i < 29) ? sv[i] : conn;
    #pragma unroll
    for (int o = 32; o > 0; o >>= 1) v += __shfl_down(v, o);
    if (lane == 0) red[wid][i] = v;
  }
  __syncthreads();
  if (t < 30) {
    float s = red[0][t] + red[1][t] + red[2][t] + red[3][t];
    atomicAdd(t == 29 ? &scal[1] : &scal[32 + t], s);
  }
}

// ---------- final scalar loss ----------
__global__ void k_finalize(const float* __restrict__ scal, float* __restrict__ out_loss) {
  if (threadIdx.x == 0 && blockIdx.x == 0) {
    float m = scal[0], conn = scal[1];
    float ss = 0.f;
    for (int k = 0; k < KCL - 1; ++k) { float s = scal[32 + k]; ss += s * s; }
    float cs2 = 0.f;
    for (int k = 0; k < KCL; ++k) { float cv = scal[2 + k]; cs2 += cv * cv; }
    float avg = ss / (2.f * m);
    float modularity = -(conn - avg) / (2.f * m);
    float reg = sqrtf(cs2 + 1e-9f) * sqrtf((float)KCL) / (float)N_NODES - 1.f;
    out_loss[0] = modularity + 0.01f * reg;
  }
}

extern "C" void kernel_launch(void* const* d_in, const int* in_sizes, int n_in,
                              void* d_out, int out_size, void* d_ws, size_t ws_size,
                              hipStream_t stream) {
  const float* x   = (const float*)d_in[0];
  const int*   ei  = (const int*)d_in[1];
  const float* ea  = (const float*)d_in[2];
  const float* Wc1 = (const float*)d_in[3];
  const float* bc1 = (const float*)d_in[4];
  const float* Wl1 = (const float*)d_in[5];
  const float* bl1 = (const float*)d_in[6];
  const float* Wc2 = (const float*)d_in[7];
  const float* bc2 = (const float*)d_in[8];
  const float* Wl2 = (const float*)d_in[9];
  const float* bl2 = (const float*)d_in[10];
  float* out = (float*)d_out;

  float* ws = (float*)d_ws;
  size_t o = 0;
  int*   cd8    = (int*)(ws + o); o += (size_t)NCOPY * N_NODES * 2;  // zeroed {cnt,deg}
  float* scal   = ws + o; o += 64;                                   // zeroed
  size_t zero_floats = o;
  int*   off8   = (int*)(ws + o); o += (size_t)N_NODES * NCOPY + 8;
  int*   blocktot = (int*)(ws + o); o += 128;
  int*   blockoff = (int*)(ws + o); o += 128;
  float* dis    = ws + o; o += N_NODES;
  int2*  csr    = (int2*)(ws + o); o += (size_t)N_EDGES * 2;     // (src, pn)
  ushort* WT1   = (ushort*)(ws + o); o += (size_t)512 * F_IN / 2;
  ushort* WT2   = (ushort*)(ws + o); o += (size_t)64 * HID / 2;
  uchar* hconv_f8 = (uchar*)(ws + o); o += (size_t)N_NODES * HID / 4;
  ushort* base1b = (ushort*)(ws + o); o += (size_t)N_NODES * HID / 2;
  ushort* h1b   = (ushort*)(ws + o); o += (size_t)N_NODES * HID / 2;
  uchar* hconv2f8 = (uchar*)(ws + o); o += (size_t)N_NODES * 32 / 4;
  float* base2p = ws + o; o += (size_t)N_NODES * 32;
  o += 64;  // slack
  if (ws_size < o * sizeof(float)) return;  // insufficient workspace — bail safely

  uchar* FXb8 = hconv_f8;   // alias: dead after k_agg1 (needs 3.2 MB < 25.6 MB)

  hipMemsetAsync(d_ws, 0, zero_floats * sizeof(float), stream);

  k_cnt8<<<N_EDGES / 1024, 256, 0, stream>>>(ei, ea, cd8, scal);
  k_scanA<<<98, 1024, 0, stream>>>(cd8, off8, blocktot);
  k_scanB<<<1, 64, 0, stream>>>(blocktot, blockoff);
  k_scanC<<<(N_NODES * NCOPY + 256) / 256, 256, 0, stream>>>(off8, blockoff);
  k_dis<<<(N_NODES + 255) / 256, 256, 0, stream>>>(cd8, dis);
  k_csrfill8<<<N_EDGES / 1024, 256, 0, stream>>>(ei, ea, dis, cd8, off8, csr);
  k_wprep<<<64, 256, 0, stream>>>(Wc1, Wl1, WT1);
  k_wprep2<<<16, 256, 0, stream>>>(Wc2, Wl2, WT2);
  k_gemm1m<<<N_NODES / 32, 256, 0, stream>>>(x, WT1, bc1, bl1, dis, hconv_f8, base1b);
  k_agg1<<<N_NODES, 256, 0, stream>>>(off8, csr, (const uint*)hconv_f8, base1b, dis, h1b);
  k_gemm2m<<<(N_NODES + 63) / 64, 256, 0, stream>>>(h1b, WT2, bc2, bl2, dis, hconv2f8, base2p);
  k_agg2<<<2048, 256, 0, stream>>>(off8, csr, dis, hconv2f8, base2p, out, FXb8, scal);
  k_conn<<<N_EDGES / 1024, 256, 0, stream>>>(ei, ea, FXb8, scal);
  k_finalize<<<1, 64, 0, stream>>>(scal, out + (size_t)N_NODES * KCL);
}

// Round 14
// 834.845 us; speedup vs baseline: 1.2073x; 1.2073x over previous
//
#include <hip/hip_runtime.h>
#include <hip/hip_bf16.h>
#include <math.h>

#define N_NODES 100000
#define N_EDGES 3200000
#define F_IN 128
#define HID 256
#define KCL 30
#define NCOPY 8

typedef unsigned int uint;
typedef unsigned short ushort;
typedef unsigned char uchar;
typedef __attribute__((ext_vector_type(8))) short bf16x8;
typedef __attribute__((ext_vector_type(4))) float f32x4;
typedef __attribute__((ext_vector_type(2))) float f32x2;

static __device__ __forceinline__ float bf2f(ushort u) {
  return __uint_as_float(((uint)u) << 16);
}
static __device__ __forceinline__ ushort f2bf(float f) {
  uint u = __float_as_uint(f);
  uint r = (u + 0x7FFF + ((u >> 16) & 1)) >> 16;   // round-to-nearest-even
  return (ushort)r;
}

// ---- fp8 e4m3 (OCP) encode/decode: HW cvt if available, software fallback ----
static __device__ __forceinline__ uchar f2fp8(float f) {
#if __has_builtin(__builtin_amdgcn_cvt_pk_fp8_f32)
  return (uchar)(__builtin_amdgcn_cvt_pk_fp8_f32(f, f, 0, false) & 0xFF);
#else
  uint u = __float_as_uint(f);
  uint s = (u >> 24) & 0x80u;
  float a = fabsf(f);
  if (a >= 448.f) return (uchar)(s | 0x7E);
  if (a < 0.015625f) {
    int q = (int)rintf(a * 512.f);
    return (uchar)(s | (q > 8 ? 8 : q));
  }
  int e = ((int)((u >> 23) & 0xFF)) - 127;
  float step = __uint_as_float((uint)(127 + e - 3) << 23);
  int q = (int)rintf(a / step);
  if (q == 16) { e += 1; q = 8; }
  return (uchar)(s | ((e + 7) << 3) | (q - 8));
#endif
}
static __device__ __forceinline__ float fp82f_sw(uchar b) {
  uint s = ((uint)(b & 0x80u)) << 24;
  uint em = b & 0x7Fu;
  float mag;
  if ((em >> 3) == 0) mag = (float)em * 0.001953125f;
  else mag = __uint_as_float((((em >> 3) + 120) << 23) | ((em & 7u) << 20));
  return __uint_as_float(s | __float_as_uint(mag));
}
static __device__ __forceinline__ void fp8x4_dec(uint u, float* o) {
#if __has_builtin(__builtin_amdgcn_cvt_pk_f32_fp8)
  f32x2 lo = __builtin_amdgcn_cvt_pk_f32_fp8((int)u, false);
  f32x2 hi = __builtin_amdgcn_cvt_pk_f32_fp8((int)u, true);
  o[0] = lo.x; o[1] = lo.y; o[2] = hi.x; o[3] = hi.y;
#else
  o[0] = fp82f_sw(u & 0xFF); o[1] = fp82f_sw((u >> 8) & 0xFF);
  o[2] = fp82f_sw((u >> 16) & 0xFF); o[3] = fp82f_sw((u >> 24) & 0xFF);
#endif
}
static __device__ __forceinline__ float fp81_dec(uchar b) {
#if __has_builtin(__builtin_amdgcn_cvt_pk_f32_fp8)
  f32x2 lo = __builtin_amdgcn_cvt_pk_f32_fp8((int)(uint)b, false);
  return lo.x;
#else
  return fp82f_sw(b);
#endif
}
static __device__ __forceinline__ void dec29(uint4 lo, uint4 hi, float* f) {
  fp8x4_dec(lo.x, f + 0);  fp8x4_dec(lo.y, f + 4);
  fp8x4_dec(lo.z, f + 8);  fp8x4_dec(lo.w, f + 12);
  fp8x4_dec(hi.x, f + 16); fp8x4_dec(hi.y, f + 20);
  fp8x4_dec(hi.z, f + 24);
  f[28] = fp81_dec((uchar)(hi.w & 0xFF));
}

// scal layout: [0]=m, [1]=connectivity, [2..31]=colsum(30), [32..60]=svec(29)

// ---------- cnt8: XCD-privatized edge-count histogram (keyed by col) ----------
__global__ __launch_bounds__(256) void k_cnt8(const int* __restrict__ ei,
                                              int* __restrict__ cnt8) {
  int e = blockIdx.x * 256 + threadIdx.x;
  int g = blockIdx.x & (NCOPY - 1);
  int c = ei[N_EDGES + e];
  atomicAdd(cnt8 + (size_t)g * N_NODES + c, 1);
}

// ---------- scanA ----------
__global__ __launch_bounds__(1024) void k_scanA(const int* __restrict__ cnt8,
                                                int* __restrict__ off8,
                                                int* __restrict__ blocktot) {
  __shared__ int wsum[16];
  const int t = threadIdx.x;
  const int lane = t & 63, wid = t >> 6;
  int node = blockIdx.x * 1024 + t;
  int v[NCOPY];
  int tot = 0;
  if (node < N_NODES) {
    #pragma unroll
    for (int g = 0; g < NCOPY; ++g) {
      int x = cnt8[(size_t)g * N_NODES + node];
      v[g] = tot;
      tot += x;
    }
  } else {
    #pragma unroll
    for (int g = 0; g < NCOPY; ++g) v[g] = 0;
  }
  int x = tot;
  #pragma unroll
  for (int o = 1; o < 64; o <<= 1) {
    int y = __shfl_up(x, o);
    if (lane >= o) x += y;
  }
  if (lane == 63) wsum[wid] = x;
  __syncthreads();
  if (t < 16) {
    int s = wsum[t];
    #pragma unroll
    for (int o = 1; o < 16; o <<= 1) {
      int y = __shfl_up(s, o);
      if (t >= o) s += y;
    }
    wsum[t] = s;
  }
  __syncthreads();
  int excl = (wid ? wsum[wid - 1] : 0) + x - tot;
  if (node < N_NODES) {
    #pragma unroll
    for (int g = 0; g < NCOPY; ++g) off8[(size_t)node * NCOPY + g] = excl + v[g];
  }
  if (t == 0) blocktot[blockIdx.x] = wsum[15];
}

// ---------- scanB ----------
__global__ void k_scanB(const int* __restrict__ blocktot, int* __restrict__ blockoff) {
  if (threadIdx.x == 0 && blockIdx.x == 0) {
    int acc = 0;
    for (int b = 0; b < 98; ++b) { blockoff[b] = acc; acc += blocktot[b]; }
  }
}

// ---------- scanC ----------
__global__ __launch_bounds__(256) void k_scanC(int* __restrict__ off8,
                                               const int* __restrict__ blockoff) {
  int idx = blockIdx.x * 256 + threadIdx.x;
  if (idx > N_NODES * NCOPY) return;
  if (idx == N_NODES * NCOPY) { off8[idx] = N_EDGES; return; }
  off8[idx] += blockoff[idx >> 13];
}

// ---------- csrfill8: scatter packed (src, w) int2 — one random line per edge ----------
__global__ __launch_bounds__(256) void k_csrfill8(const int* __restrict__ ei,
                                                  const float* __restrict__ w,
                                                  int* __restrict__ cnt8,
                                                  const int* __restrict__ off8,
                                                  int2* __restrict__ csr) {
  int e = blockIdx.x * 256 + threadIdx.x;
  int g = blockIdx.x & (NCOPY - 1);
  int r = ei[e], c = ei[N_EDGES + e];
  int idx = atomicSub(cnt8 + (size_t)g * N_NODES + c, 1) - 1;
  int pos = off8[(size_t)c * NCOPY + g] + idx;
  csr[pos] = make_int2(r, __float_as_int(w[e]));
}

// ---------- degdis: dis[n] = rsqrt(row-sum of w + 1); block-reduce partial m ----------
__global__ __launch_bounds__(256) void k_degdis(const int* __restrict__ off8,
                                                const int2* __restrict__ csr,
                                                float* __restrict__ dis,
                                                float* __restrict__ m_out) {
  int n = blockIdx.x * 256 + threadIdx.x;
  float s = 0.f;
  if (n < N_NODES) {
    int e0 = off8[(size_t)n * NCOPY];
    int e1 = off8[(size_t)(n + 1) * NCOPY];
    for (int j = e0; j < e1; ++j) s += __int_as_float(csr[j].y);
    dis[n] = rsqrtf(s + 1.f);
  }
  float v = s;
  #pragma unroll
  for (int o = 32; o > 0; o >>= 1) v += __shfl_down(v, o);
  __shared__ float ls[4];
  int lane = threadIdx.x & 63, wid = threadIdx.x >> 6;
  if (lane == 0) ls[wid] = v;
  __syncthreads();
  if (threadIdx.x == 0) atomicAdd(m_out, ls[0] + ls[1] + ls[2] + ls[3]);
}

// ---------- pn: fold dis[src] into csr.y in place ----------
__global__ __launch_bounds__(256) void k_pn(int2* __restrict__ csr,
                                            const float* __restrict__ dis) {
  int j = blockIdx.x * 256 + threadIdx.x;
  int2 e = csr[j];
  csr[j] = make_int2(e.x, __float_as_int(__int_as_float(e.y) * dis[e.x]));
}

// ---------- wprep ----------
__global__ __launch_bounds__(256) void k_wprep(const float* __restrict__ Wc,
                                               const float* __restrict__ Wl,
                                               ushort* __restrict__ WT1) {
  int idx = blockIdx.x * 256 + threadIdx.x;
  int vc = idx >> 5;
  int kq = (idx & 31) * 4;
  const float* W = (vc < HID) ? Wc : Wl;
  int c = vc & (HID - 1);
  ushort4 u;
  u.x = f2bf(W[(size_t)(kq + 0) * HID + c]);
  u.y = f2bf(W[(size_t)(kq + 1) * HID + c]);
  u.z = f2bf(W[(size_t)(kq + 2) * HID + c]);
  u.w = f2bf(W[(size_t)(kq + 3) * HID + c]);
  *(ushort4*)(WT1 + (size_t)vc * F_IN + kq) = u;
}

// ---------- wprep2 ----------
__global__ __launch_bounds__(256) void k_wprep2(const float* __restrict__ Wc,
                                                const float* __restrict__ Wl,
                                                ushort* __restrict__ WT2) {
  int idx = blockIdx.x * 256 + threadIdx.x;
  int vc = idx >> 6;
  int kq = (idx & 63) * 4;
  const float* W = (vc < 32) ? Wc : Wl;
  int c = vc & 31;
  ushort4 u = make_ushort4(0, 0, 0, 0);
  if (c < KCL) {
    u.x = f2bf(W[(size_t)(kq + 0) * KCL + c]);
    u.y = f2bf(W[(size_t)(kq + 1) * KCL + c]);
    u.z = f2bf(W[(size_t)(kq + 2) * KCL + c]);
    u.w = f2bf(W[(size_t)(kq + 3) * KCL + c]);
  }
  *(ushort4*)(WT2 + (size_t)vc * HID + kq) = u;
}

// ---------- layer-1 dual GEMM via MFMA bf16; hconv out fp8 (LDS repack), base1 out bf16 ----------
__global__ __launch_bounds__(256) void k_gemm1m(const float* __restrict__ x,
                                                const ushort* __restrict__ WT1,
                                                const float* __restrict__ bc,
                                                const float* __restrict__ bl,
                                                const float* __restrict__ dis,
                                                uchar* __restrict__ hconv_f8,
                                                ushort* __restrict__ base1b) {
  __shared__ ushort xs[32 * F_IN];   // 8 KB: bf16 x-tile, then reused as fp8 [32][256] tile
  uchar* xs8 = (uchar*)xs;
  const int t = threadIdx.x;
  const int lane = t & 63, wid = t >> 6;
  const int m0 = blockIdx.x * 32;
  {
    int row = t >> 3, k0 = (t & 7) * 16;
    const float4* xp = (const float4*)(x + (size_t)(m0 + row) * F_IN + k0);
    #pragma unroll
    for (int q = 0; q < 4; ++q) {
      float4 v = xp[q];
      ushort4 u = make_ushort4(f2bf(v.x), f2bf(v.y), f2bf(v.z), f2bf(v.w));
      int k = k0 + q * 4;
      *(ushort4*)&xs[row * F_IN + (k ^ ((row & 7) << 3))] = u;
    }
  }
  __syncthreads();
  const int r0 = lane & 15, r1 = 16 + (lane & 15);
  const int kb = (lane >> 4) * 8;
  bf16x8 A0[4], A1[4];
  #pragma unroll
  for (int ks = 0; ks < 4; ++ks) {
    int k = ks * 32 + kb;
    A0[ks] = *(const bf16x8*)&xs[r0 * F_IN + (k ^ ((r0 & 7) << 3))];
    A1[ks] = *(const bf16x8*)&xs[r1 * F_IN + (k ^ ((r1 & 7) << 3))];
  }
  __syncthreads();   // all waves done reading xs; safe to overwrite with fp8 bytes
  const int rb = (lane >> 4) * 4;
  #pragma unroll
  for (int cb = 0; cb < 2; ++cb) {
    bf16x8 B[4][4];   // f = cs*2+cf: {C0,C1,L0,L1}
    const int vbase = cb * 128 + wid * 32 + (lane & 15);
    #pragma unroll
    for (int cs = 0; cs < 2; ++cs)
      #pragma unroll
      for (int cf = 0; cf < 2; ++cf)
        #pragma unroll
        for (int ks = 0; ks < 4; ++ks) {
          int vc = cs * HID + vbase + cf * 16;
          B[cs * 2 + cf][ks] = *(const bf16x8*)(WT1 + (size_t)vc * F_IN + ks * 32 + kb);
        }
    f32x4 acc[2][4];
    #pragma unroll
    for (int fm = 0; fm < 2; ++fm)
      #pragma unroll
      for (int f = 0; f < 4; ++f) acc[fm][f] = (f32x4){0.f, 0.f, 0.f, 0.f};
    #pragma unroll
    for (int ks = 0; ks < 4; ++ks) {
      #pragma unroll
      for (int f = 0; f < 4; ++f) {
        acc[0][f] = __builtin_amdgcn_mfma_f32_16x16x32_bf16(A0[ks], B[f][ks], acc[0][f], 0, 0, 0);
        acc[1][f] = __builtin_amdgcn_mfma_f32_16x16x32_bf16(A1[ks], B[f][ks], acc[1][f], 0, 0, 0);
      }
    }
    #pragma unroll
    for (int cf = 0; cf < 2; ++cf) {
      int c = cb * 128 + wid * 32 + cf * 16 + (lane & 15);
      float bcv = bc[c], blv = bl[c];
      #pragma unroll
      for (int fm = 0; fm < 2; ++fm) {
        #pragma unroll
        for (int r = 0; r < 4; ++r) {
          int lrow = fm * 16 + rb + r;
          int row = m0 + lrow;
          float hc = acc[fm][cf][r];
          float hl = acc[fm][2 + cf][r];
          float d = dis[row];
          xs8[lrow * 256 + c] = f2fp8(hc);
          base1b[(size_t)row * HID + c] = f2bf(hl + blv + bcv + d * d * hc);
        }
      }
    }
  }
  __syncthreads();
  {
    int row = t >> 3, c0 = (t & 7) * 32;
    uint4 a = *(const uint4*)&xs8[row * 256 + c0];
    uint4 b = *(const uint4*)&xs8[row * 256 + c0 + 16];
    uchar* dst = hconv_f8 + (size_t)(m0 + row) * 256 + c0;
    *(uint4*)dst = a;
    *(uint4*)(dst + 16) = b;
  }
}

// ---------- layer-1 aggregation over fp8 hconv (4-deep gather pipeline) ----------
__global__ __launch_bounds__(256) void k_agg1(const int* __restrict__ off8,
                                              const int2* __restrict__ csr,
                                              const uint* __restrict__ hconv_u32,
                                              const ushort* __restrict__ base1b,
                                              const float* __restrict__ dis,
                                              ushort* __restrict__ h1b) {
  const int n = blockIdx.x;
  const int t = threadIdx.x;
  const int lane = t & 63, wid = t >> 6;
  const int e0 = off8[(size_t)n * NCOPY];
  const int e1 = off8[(size_t)(n + 1) * NCOPY];
  __shared__ int2 s_e[256];
  __shared__ float red[4][256];
  float acc0 = 0.f, acc1 = 0.f, acc2 = 0.f, acc3 = 0.f;
  for (int jb = e0; jb < e1; jb += 256) {
    int cn = min(256, e1 - jb);
    __syncthreads();
    if (t < cn) s_e[t] = csr[jb + t];
    __syncthreads();
    int j = wid;
    // 4 edges in flight per wave iteration
    for (; j + 12 < cn; j += 16) {
      int2 eA = s_e[j];
      int2 eB = s_e[j + 4];
      int2 eC = s_e[j + 8];
      int2 eD = s_e[j + 12];
      uint uA = hconv_u32[(size_t)eA.x * 64 + lane];
      uint uB = hconv_u32[(size_t)eB.x * 64 + lane];
      uint uC = hconv_u32[(size_t)eC.x * 64 + lane];
      uint uD = hconv_u32[(size_t)eD.x * 64 + lane];
      float nA = __int_as_float(eA.y);
      float nB = __int_as_float(eB.y);
      float nC = __int_as_float(eC.y);
      float nD = __int_as_float(eD.y);
      float vA[4], vB[4], vC[4], vD[4];
      fp8x4_dec(uA, vA);
      fp8x4_dec(uB, vB);
      fp8x4_dec(uC, vC);
      fp8x4_dec(uD, vD);
      acc0 = fmaf(nA, vA[0], acc0); acc1 = fmaf(nA, vA[1], acc1);
      acc2 = fmaf(nA, vA[2], acc2); acc3 = fmaf(nA, vA[3], acc3);
      acc0 = fmaf(nB, vB[0], acc0); acc1 = fmaf(nB, vB[1], acc1);
      acc2 = fmaf(nB, vB[2], acc2); acc3 = fmaf(nB, vB[3], acc3);
      acc0 = fmaf(nC, vC[0], acc0); acc1 = fmaf(nC, vC[1], acc1);
      acc2 = fmaf(nC, vC[2], acc2); acc3 = fmaf(nC, vC[3], acc3);
      acc0 = fmaf(nD, vD[0], acc0); acc1 = fmaf(nD, vD[1], acc1);
      acc2 = fmaf(nD, vD[2], acc2); acc3 = fmaf(nD, vD[3], acc3);
    }
    for (; j + 4 < cn; j += 8) {
      int2 eA = s_e[j];
      int2 eB = s_e[j + 4];
      float nA = __int_as_float(eA.y);
      float nB = __int_as_float(eB.y);
      uint uA = hconv_u32[(size_t)eA.x * 64 + lane];
      uint uB = hconv_u32[(size_t)eB.x * 64 + lane];
      float vA[4], vB[4];
      fp8x4_dec(uA, vA);
      fp8x4_dec(uB, vB);
      acc0 = fmaf(nA, vA[0], acc0); acc1 = fmaf(nA, vA[1], acc1);
      acc2 = fmaf(nA, vA[2], acc2); acc3 = fmaf(nA, vA[3], acc3);
      acc0 = fmaf(nB, vB[0], acc0); acc1 = fmaf(nB, vB[1], acc1);
      acc2 = fmaf(nB, vB[2], acc2); acc3 = fmaf(nB, vB[3], acc3);
    }
    if (j < cn) {
      int2 eA = s_e[j];
      float nA = __int_as_float(eA.y);
      uint uA = hconv_u32[(size_t)eA.x * 64 + lane];
      float vA[4];
      fp8x4_dec(uA, vA);
      acc0 = fmaf(nA, vA[0], acc0); acc1 = fmaf(nA, vA[1], acc1);
      acc2 = fmaf(nA, vA[2], acc2); acc3 = fmaf(nA, vA[3], acc3);
    }
  }
  __syncthreads();
  ((float4*)red[wid])[lane] = make_float4(acc0, acc1, acc2, acc3);
  __syncthreads();
  float dn = dis[n];
  float v = dn * (red[0][t] + red[1][t] + red[2][t] + red[3][t]) + bf2f(base1b[(size_t)n * HID + t]);
  h1b[(size_t)n * HID + t] = f2bf(fmaxf(v, 0.f));
}

// ---------- layer-2 dual GEMM via MFMA bf16; hconv2 out fp8 (stride 32 B) ----------
__global__ __launch_bounds__(256) void k_gemm2m(const ushort* __restrict__ h1b,
                                                const ushort* __restrict__ WT2,
                                                const float* __restrict__ bc,
                                                const float* __restrict__ bl,
                                                const float* __restrict__ dis,
                                                uchar* __restrict__ hconv2f8,
                                                float* __restrict__ base2p) {
  __shared__ ushort hs[64 * HID];    // 32 KB, XOR-swizzled bf16
  const int t = threadIdx.x;
  const int lane = t & 63, wid = t >> 6;
  const int n0 = blockIdx.x * 64;
  {
    int row = t >> 2, kq = (t & 3) * 64;
    int gn = n0 + row;
    #pragma unroll
    for (int q = 0; q < 8; ++q) {
      int k = kq + q * 8;
      uint4 u = make_uint4(0, 0, 0, 0);
      if (gn < N_NODES) u = *(const uint4*)(h1b + (size_t)gn * HID + k);
      *(uint4*)&hs[row * HID + (k ^ ((row & 7) << 3))] = u;
    }
  }
  __syncthreads();
  const int lr = wid * 16 + (lane & 15);
  const int kb = (lane >> 4) * 8;
  f32x4 acc[4];
  #pragma unroll
  for (int f = 0; f < 4; ++f) acc[f] = (f32x4){0.f, 0.f, 0.f, 0.f};
  #pragma unroll
  for (int ks = 0; ks < 8; ++ks) {
    int k = ks * 32 + kb;
    bf16x8 A = *(const bf16x8*)&hs[lr * HID + (k ^ ((lr & 7) << 3))];
    #pragma unroll
    for (int f = 0; f < 4; ++f) {
      int vc = f * 16 + (lane & 15);
      bf16x8 B = *(const bf16x8*)(WT2 + (size_t)vc * HID + k);
      acc[f] = __builtin_amdgcn_mfma_f32_16x16x32_bf16(A, B, acc[f], 0, 0, 0);
    }
  }
  const int rb = (lane >> 4) * 4;
  #pragma unroll
  for (int cf = 0; cf < 2; ++cf) {
    int c = cf * 16 + (lane & 15);
    if (c < KCL) {
      float bcv = bc[c], blv = bl[c];
      #pragma unroll
      for (int r = 0; r < 4; ++r) {
        int row = n0 + wid * 16 + rb + r;
        if (row < N_NODES) {
          float hc = acc[cf][r];
          float hl = acc[2 + cf][r];
          float d = dis[row];
          hconv2f8[(size_t)row * 32 + c] = f2fp8(hc);
          base2p[(size_t)row * 32 + c] = hl + blv + bcv + d * d * hc;
        }
      }
    }
  }
}

// ---------- layer-2 aggregation + softmax + FX(fp32) + FXb8(fp8, stride 32B) + colsum ----------
__global__ __launch_bounds__(256) void k_agg2(const int* __restrict__ off8,
                                              const int2* __restrict__ csr,
                                              const float* __restrict__ dis,
                                              const uchar* __restrict__ hconv2f8,
                                              const float* __restrict__ base2p,
                                              float* __restrict__ FX,
                                              uchar* __restrict__ FXb8,
                                              float* __restrict__ scal) {
  const int t = threadIdx.x;
  const int lane = t & 63, wid = t >> 6;
  const int half = lane >> 5, c = lane & 31;
  const int nwaves = gridDim.x * 4;
  const int gw = blockIdx.x * 4 + wid;
  float cs_acc = 0.f;
  for (int n = gw; n < N_NODES; n += nwaves) {
    int e0 = off8[(size_t)n * NCOPY];
    int e1 = off8[(size_t)(n + 1) * NCOPY];
    float accA = 0.f, accB = 0.f;
    int j = e0 + half;
    for (; j + 2 < e1; j += 4) {
      int2 eA = csr[j];
      int2 eB = csr[j + 2];
      float p0 = __int_as_float(eA.y);
      float p1 = __int_as_float(eB.y);
      uchar b0 = hconv2f8[(size_t)eA.x * 32 + c];
      uchar b1 = hconv2f8[(size_t)eB.x * 32 + c];
      float v0 = (c < KCL) ? fp81_dec(b0) : 0.f;
      float v1 = (c < KCL) ? fp81_dec(b1) : 0.f;
      accA = fmaf(p0, v0, accA);
      accB = fmaf(p1, v1, accB);
    }
    if (j < e1) {
      int2 eA = csr[j];
      float p0 = __int_as_float(eA.y);
      uchar b0 = hconv2f8[(size_t)eA.x * 32 + c];
      float v0 = (c < KCL) ? fp81_dec(b0) : 0.f;
      accA = fmaf(p0, v0, accA);
    }
    float acc = accA + accB;
    acc += __shfl(acc, lane ^ 32);
    float out = (c < KCL) ? acc * dis[n] + base2p[(size_t)n * 32 + c] : -1e30f;
    float mx = out;
    #pragma unroll
    for (int o = 16; o > 0; o >>= 1) mx = fmaxf(mx, __shfl_xor(mx, o));
    float p = (c < KCL) ? __expf(out - mx) : 0.f;
    float sum = p;
    #pragma unroll
    for (int o = 16; o > 0; o >>= 1) sum += __shfl_xor(sum, o);
    float fx = p / sum;
    fx = fminf(fmaxf(fx, 1e-9f), 1.f - 1e-9f);
    if (half == 0 && c < KCL) {
      FX[(size_t)n * KCL + c] = fx;
      FXb8[(size_t)n * 32 + c] = f2fp8(fx);
    }
    cs_acc += (c < KCL) ? fx : 0.f;
  }
  __shared__ float red_cs[4][32];
  if (half == 0) red_cs[wid][c] = cs_acc;
  __syncthreads();
  if (t < KCL) {
    float a = red_cs[0][t] + red_cs[1][t] + red_cs[2][t] + red_cs[3][t];
    atomicAdd(&scal[2 + t], a);
  }
}

// ---------- connectivity + svec, edge-parallel over fp8 FX shadow (32 B rows, L2-resident) ----------
__global__ __launch_bounds__(256) void k_conn(const int* __restrict__ ei,
                                              const float* __restrict__ w,
                                              const uchar* __restrict__ FXb8,
                                              float* __restrict__ scal) {
  const int t = threadIdx.x;
  const int lane = t & 63, wid = t >> 6;
  const size_t e0 = ((size_t)blockIdx.x * 256 + t) * 4;
  float sv[29];
  #pragma unroll
  for (int k = 0; k < 29; ++k) sv[k] = 0.f;
  float conn = 0.f;
  int4 rr = *(const int4*)(ei + e0);
  int4 cc = *(const int4*)(ei + N_EDGES + e0);
  float4 ww = *(const float4*)(w + e0);
  const int rA[4] = {rr.x, rr.y, rr.z, rr.w};
  const int cA[4] = {cc.x, cc.y, cc.z, cc.w};
  const float wA[4] = {ww.x, ww.y, ww.z, ww.w};
  #pragma unroll
  for (int q = 0; q < 4; ++q) {
    int r = rA[q], cN = cA[q];
    float wv = wA[q];
    uint4 alo = *(const uint4*)(FXb8 + (size_t)r * 32);
    uint4 ahi = *(const uint4*)(FXb8 + (size_t)r * 32 + 16);
    uint4 blo = *(const uint4*)(FXb8 + (size_t)cN * 32);
    uint4 bhi = *(const uint4*)(FXb8 + (size_t)cN * 32 + 16);
    float fa[29], fb[29];
    dec29(alo, ahi, fa);
    dec29(blo, bhi, fb);
    float dot = 0.f;
    #pragma unroll
    for (int k = 0; k < 29; ++k) {
      dot += fa[k] * fb[k];
      sv[k] = fmaf(wv, fa[k], sv[k]);
    }
    conn = fmaf(wv, dot, conn);
  }
  __shared__ float red[4][30];
  #pragma unroll
  for (int i = 0; i < 30; ++i) {
    float v = (i < 29) ? sv[i] : conn;
    #pragma unroll
    for (int o = 32; o > 0; o >>= 1) v += __shfl_down(v, o);
    if (lane == 0) red[wid][i] = v;
  }
  __syncthreads();
  if (t < 30) {
    float s = red[0][t] + red[1][t] + red[2][t] + red[3][t];
    atomicAdd(t == 29 ? &scal[1] : &scal[32 + t], s);
  }
}

// ---------- final scalar loss ----------
__global__ void k_finalize(const float* __restrict__ scal, float* __restrict__ out_loss) {
  if (threadIdx.x == 0 && blockIdx.x == 0) {
    float m = scal[0], conn = scal[1];
    float ss = 0.f;
    for (int k = 0; k < KCL - 1; ++k) { float s = scal[32 + k]; ss += s * s; }
    float cs2 = 0.f;
    for (int k = 0; k < KCL; ++k) { float cv = scal[2 + k]; cs2 += cv * cv; }
    float avg = ss / (2.f * m);
    float modularity = -(conn - avg) / (2.f * m);
    float reg = sqrtf(cs2 + 1e-9f) * sqrtf((float)KCL) / (float)N_NODES - 1.f;
    out_loss[0] = modularity + 0.01f * reg;
  }
}

extern "C" void kernel_launch(void* const* d_in, const int* in_sizes, int n_in,
                              void* d_out, int out_size, void* d_ws, size_t ws_size,
                              hipStream_t stream) {
  const float* x   = (const float*)d_in[0];
  const int*   ei  = (const int*)d_in[1];
  const float* ea  = (const float*)d_in[2];
  const float* Wc1 = (const float*)d_in[3];
  const float* bc1 = (const float*)d_in[4];
  const float* Wl1 = (const float*)d_in[5];
  const float* bl1 = (const float*)d_in[6];
  const float* Wc2 = (const float*)d_in[7];
  const float* bc2 = (const float*)d_in[8];
  const float* Wl2 = (const float*)d_in[9];
  const float* bl2 = (const float*)d_in[10];
  float* out = (float*)d_out;

  float* ws = (float*)d_ws;
  size_t o = 0;
  int*   cnt8   = (int*)(ws + o); o += (size_t)NCOPY * N_NODES;  // zeroed
  float* scal   = ws + o; o += 64;                               // zeroed
  size_t zero_floats = o;
  int*   off8   = (int*)(ws + o); o += (size_t)N_NODES * NCOPY + 8;
  int*   blocktot = (int*)(ws + o); o += 128;
  int*   blockoff = (int*)(ws + o); o += 128;
  float* dis    = ws + o; o += N_NODES;
  int2*  csr    = (int2*)(ws + o); o += (size_t)N_EDGES * 2;     // (src, w->pn)
  ushort* WT1   = (ushort*)(ws + o); o += (size_t)512 * F_IN / 2;
  ushort* WT2   = (ushort*)(ws + o); o += (size_t)64 * HID / 2;
  uchar* hconv_f8 = (uchar*)(ws + o); o += (size_t)N_NODES * HID / 4;
  ushort* base1b = (ushort*)(ws + o); o += (size_t)N_NODES * HID / 2;
  ushort* h1b   = (ushort*)(ws + o); o += (size_t)N_NODES * HID / 2;
  uchar* hconv2f8 = (uchar*)(ws + o); o += (size_t)N_NODES * 32 / 4;
  float* base2p = ws + o; o += (size_t)N_NODES * 32;
  o += 64;  // slack
  if (ws_size < o * sizeof(float)) return;  // insufficient workspace — bail safely

  uchar* FXb8 = hconv_f8;   // alias: dead after k_agg1 (needs 3.2 MB < 25.6 MB)

  hipMemsetAsync(d_ws, 0, zero_floats * sizeof(float), stream);

  k_cnt8<<<N_EDGES / 256, 256, 0, stream>>>(ei, cnt8);
  k_scanA<<<98, 1024, 0, stream>>>(cnt8, off8, blocktot);
  k_scanB<<<1, 64, 0, stream>>>(blocktot, blockoff);
  k_scanC<<<(N_NODES * NCOPY + 256) / 256, 256, 0, stream>>>(off8, blockoff);
  k_csrfill8<<<N_EDGES / 256, 256, 0, stream>>>(ei, ea, cnt8, off8, csr);
  k_degdis<<<(N_NODES + 255) / 256, 256, 0, stream>>>(off8, csr, dis, scal);
  k_pn<<<N_EDGES / 256, 256, 0, stream>>>(csr, dis);
  k_wprep<<<64, 256, 0, stream>>>(Wc1, Wl1, WT1);
  k_wprep2<<<16, 256, 0, stream>>>(Wc2, Wl2, WT2);
  k_gemm1m<<<N_NODES / 32, 256, 0, stream>>>(x, WT1, bc1, bl1, dis, hconv_f8, base1b);
  k_agg1<<<N_NODES, 256, 0, stream>>>(off8, csr, (const uint*)hconv_f8, base1b, dis, h1b);
  k_gemm2m<<<(N_NODES + 63) / 64, 256, 0, stream>>>(h1b, WT2, bc2, bl2, dis, hconv2f8, base2p);
  k_agg2<<<2048, 256, 0, stream>>>(off8, csr, dis, hconv2f8, base2p, out, FXb8, scal);
  k_conn<<<N_EDGES / 1024, 256, 0, stream>>>(ei, ea, FXb8, scal);
  k_finalize<<<1, 64, 0, stream>>>(scal, out + (size_t)N_NODES * KCL);
}